// Round 7
// baseline (83.712 us; speedup 1.0000x reference)
//
#include <hip/hip_runtime.h>
#include <math.h>

#define MM 32
#define NN 8192
#define DD 64
#define KK 16

typedef float f32x4 __attribute__((ext_vector_type(4)));

// ---------------------------------------------------------------------------
// Kernel 1: per-component precompute via Woodbury.
//   Mk = I + Lambda^T P^{-1} Lambda  (16x16), P = diag(Psi + 1e-6)
//   Minv[m] = Mk^{-1} (== term1);  const[m] = log pi - 0.5*(D log2pi + logdet)
// Also exports pinv[64] and Wl[m] = P^{-1} Lambda_m.
// ---------------------------------------------------------------------------
__global__ __launch_bounds__(256) void mfa_pre(
    const float* __restrict__ pi, const float* __restrict__ Lambda,
    const float* __restrict__ Psi, float* __restrict__ Minv_out,
    float* __restrict__ const_out, float* __restrict__ pinv_out,
    float* __restrict__ Wl_out) {
  const int m = blockIdx.x;
  const int tid = threadIdx.x;
  __shared__ float lam[DD * KK];
  __shared__ float pinv[DD];
  __shared__ float Mmat[KK * KK];
  __shared__ float Lmat[KK * KK];
  __shared__ float vbuf[KK];

  for (int idx = tid; idx < DD * KK; idx += 256)
    lam[idx] = Lambda[(size_t)m * DD * KK + idx];
  if (tid < DD) pinv[tid] = 1.0f / (Psi[tid] + 1e-6f);
  __syncthreads();

  for (int idx = tid; idx < DD * KK; idx += 256)
    Wl_out[(size_t)m * DD * KK + idx] = lam[idx] * pinv[idx >> 4];
  if (tid < DD) pinv_out[tid] = pinv[tid];

  {
    const int k = tid >> 4, j = tid & 15;
    float a = 0.0f;
    for (int d = 0; d < DD; ++d)
      a += lam[d * KK + k] * lam[d * KK + j] * pinv[d];
    Mmat[tid] = a + (k == j ? 1.0f : 0.0f);
  }
  __syncthreads();

  // Cooperative right-looking Cholesky: thread r owns row r in registers.
  float lr[KK];
  if (tid < KK) {
#pragma unroll
    for (int j = 0; j < KK; ++j) lr[j] = Mmat[tid * KK + j];
  }
#pragma unroll
  for (int c = 0; c < KK; ++c) {
    if (tid < KK) vbuf[tid] = lr[c];
    __syncthreads();
    if (tid < KK) {
      const float vc = vbuf[c];
      const float dc = sqrtf(vc);
      const float lrc = lr[c] / dc;
      if (tid >= c) Lmat[tid * KK + c] = lrc;
      const float s = lr[c] / vc;
#pragma unroll
      for (int j = 0; j < KK; ++j)
        if (j > c) lr[j] -= s * vbuf[j];
    }
    __syncthreads();
  }

  if (tid < KK) {
    const int col = tid;
    float y[KK], z[KK];
#pragma unroll
    for (int i = 0; i < KK; ++i) {
      float s = (i == col) ? 1.0f : 0.0f;
#pragma unroll
      for (int p = 0; p < KK; ++p)
        if (p < i) s -= Lmat[i * KK + p] * y[p];
      y[i] = s / Lmat[i * KK + i];
    }
#pragma unroll
    for (int i = KK - 1; i >= 0; --i) {
      float s = y[i];
#pragma unroll
      for (int p = 0; p < KK; ++p)
        if (p > i) s -= Lmat[p * KK + i] * z[p];
      z[i] = s / Lmat[i * KK + i];
    }
#pragma unroll
    for (int i = 0; i < KK; ++i)
      Minv_out[(size_t)m * KK * KK + i * KK + col] = z[i];
  }

  if (tid == 0) {
    float logdetM = 0.0f;
#pragma unroll
    for (int c = 0; c < KK; ++c) logdetM += logf(Lmat[c * KK + c]);
    logdetM *= 2.0f;
    float logdetP = 0.0f;
    for (int d = 0; d < DD; ++d) logdetP -= logf(pinv[d]);
    const float LOG2PI = 1.8378770664093453f;
    const_out[m] =
        logf(pi[m] + 1e-10f) - 0.5f * (DD * LOG2PI + logdetP + logdetM);
  }
}

// ---------------------------------------------------------------------------
// Kernel 2: fused main pass, barrier-free (R6 structure). Only change vs R6:
// e_z / e_zz streams use NONTEMPORAL stores — these outputs are never
// re-read, so bypassing L2/L3 write-allocation removes cache churn from the
// 286MB write stream. Logit stores stay cached (softmax re-reads them).
// ---------------------------------------------------------------------------
__global__ __launch_bounds__(256) void mfa_main(
    const float* __restrict__ X, const float* __restrict__ mu,
    const float* __restrict__ Minv, const float* __restrict__ cconst,
    const float* __restrict__ pinvG, const float* __restrict__ WlG,
    float* __restrict__ out) {
  const int m = blockIdx.y;
  const int n0 = blockIdx.x * 256;
  const int tid = threadIdx.x;
  const int w = tid >> 6, l = tid & 63;

  __shared__ float ez_l[256 * KK];  // 16KB, wave w owns [w*64*KK, +4KB)

  const float* Wlm = WlG + (size_t)m * DD * KK;  // uniform rows
  const float* mum = mu + m * DD;
  const float* Mi = Minv + (size_t)m * KK * KK;
  const float cst = cconst[m];

  const int n = n0 + tid;

  float u[KK];
#pragma unroll
  for (int k = 0; k < KK; ++k) u[k] = 0.0f;
  float q = 0.0f;
  const float4* X4 = reinterpret_cast<const float4*>(X + (size_t)n * DD);
#pragma unroll
  for (int d4 = 0; d4 < DD / 4; ++d4) {
    const float4 xv = X4[d4];                                           // lane
    const float4 muv = *reinterpret_cast<const float4*>(mum + d4 * 4);  // unif
    const float4 piv = *reinterpret_cast<const float4*>(pinvG + d4 * 4);
    const float xs[4] = {xv.x, xv.y, xv.z, xv.w};
    const float ms[4] = {muv.x, muv.y, muv.z, muv.w};
    const float ps[4] = {piv.x, piv.y, piv.z, piv.w};
#pragma unroll
    for (int s = 0; s < 4; ++s) {
      const int d = d4 * 4 + s;
      const float df = xs[s] - ms[s];
      q += df * df * ps[s];
      const float4* wr = reinterpret_cast<const float4*>(Wlm + d * KK);
#pragma unroll
      for (int k4 = 0; k4 < 4; ++k4) {
        const float4 wv = wr[k4];  // uniform
        u[k4 * 4 + 0] += wv.x * df;
        u[k4 * 4 + 1] += wv.y * df;
        u[k4 * 4 + 2] += wv.z * df;
        u[k4 * 4 + 3] += wv.w * df;
      }
    }
  }

  float ez[KK];
  float udot = 0.0f;
#pragma unroll
  for (int i = 0; i < KK; ++i) {
    const float4* mr = reinterpret_cast<const float4*>(Mi + i * KK);
    float s = 0.0f;
#pragma unroll
    for (int j4 = 0; j4 < 4; ++j4) {
      const float4 mv = mr[j4];  // uniform
      s += mv.x * u[j4 * 4 + 0] + mv.y * u[j4 * 4 + 1] +
           mv.z * u[j4 * 4 + 2] + mv.w * u[j4 * 4 + 3];
    }
    ez[i] = s;
    udot += u[i] * s;
  }
  const float maha = q - udot;
  out[(size_t)n * MM + m] = cst - 0.5f * maha;  // logit (cached store)

#pragma unroll
  for (int k = 0; k < KK; ++k) ez_l[tid * KK + k] = ez[k];

  // ---- wave-local phase switch (no __syncthreads) ----
  __builtin_amdgcn_wave_barrier();
  asm volatile("s_waitcnt lgkmcnt(0)" ::: "memory");

  const int sbase = n0 + w * 64;  // first sample owned by this wave
  const f32x4* ezl4 =
      reinterpret_cast<const f32x4*>(ez_l + (size_t)w * 64 * KK);

  // e_z out: wave's 64 samples * 16 floats = 256 float4, coalesced, NT
  f32x4* ezo = reinterpret_cast<f32x4*>(
      out + (size_t)NN * MM + ((size_t)m * NN + sbase) * KK);
#pragma unroll
  for (int it = 0; it < 4; ++it)
    __builtin_nontemporal_store(ezl4[it * 64 + l], &ezo[it * 64 + l]);

  // e_zz out: per iteration the wave writes one sample's full 16x16 tile
  // (64 lanes x float4 = 1KB, coalesced, NT). lane l: row l>>2, col-quad l&3.
  const int i_ = l >> 2, jq = l & 3;
  const f32x4 mreg = reinterpret_cast<const f32x4*>(Mi)[l];  // per-lane
  f32x4* zzo = reinterpret_cast<f32x4*>(out + (size_t)NN * MM +
                                        (size_t)MM * NN * KK) +
               ((size_t)m * NN + sbase) * 64;
#pragma unroll 4
  for (int nl = 0; nl < 64; ++nl) {
    const float ezi = ez_l[((size_t)w * 64 + nl) * KK + i_];
    const f32x4 ezj = ezl4[nl * 4 + jq];
    const f32x4 o = mreg + ezi * ezj;
    __builtin_nontemporal_store(o, &zzo[nl * 64 + l]);
  }
}

// ---------------------------------------------------------------------------
// Kernel 3: in-place softmax over the M=32 logits per sample.
// ---------------------------------------------------------------------------
__global__ __launch_bounds__(256) void mfa_softmax(float* __restrict__ out) {
  const int n = blockIdx.x * 256 + threadIdx.x;
  float4* p = reinterpret_cast<float4*>(out) + (size_t)n * (MM / 4);
  float v[MM];
#pragma unroll
  for (int i = 0; i < MM / 4; ++i) {
    const float4 t = p[i];
    v[4 * i] = t.x; v[4 * i + 1] = t.y; v[4 * i + 2] = t.z; v[4 * i + 3] = t.w;
  }
  float mx = -3.4e38f;
#pragma unroll
  for (int i = 0; i < MM; ++i) mx = fmaxf(mx, v[i]);
  float s = 0.0f;
#pragma unroll
  for (int i = 0; i < MM; ++i) { v[i] = expf(v[i] - mx); s += v[i]; }
  const float inv = 1.0f / s;
#pragma unroll
  for (int i = 0; i < MM / 4; ++i) {
    float4 t;
    t.x = v[4 * i] * inv; t.y = v[4 * i + 1] * inv;
    t.z = v[4 * i + 2] * inv; t.w = v[4 * i + 3] * inv;
    p[i] = t;
  }
}

extern "C" void kernel_launch(void* const* d_in, const int* in_sizes, int n_in,
                              void* d_out, int out_size, void* d_ws,
                              size_t ws_size, hipStream_t stream) {
  const float* X = (const float*)d_in[0];
  const float* pi = (const float*)d_in[1];
  const float* mu = (const float*)d_in[2];
  const float* Lambda = (const float*)d_in[3];
  const float* Psi = (const float*)d_in[4];
  float* out = (float*)d_out;

  float* Minv = (float*)d_ws;             // 32*256 floats
  float* cconst = Minv + MM * KK * KK;    // 32
  float* pinvG = cconst + MM;             // 64
  float* WlG = pinvG + DD;                // 32*1024

  mfa_pre<<<MM, 256, 0, stream>>>(pi, Lambda, Psi, Minv, cconst, pinvG, WlG);
  mfa_main<<<dim3(NN / 256, MM), 256, 0, stream>>>(X, mu, Minv, cconst, pinvG,
                                                   WlG, out);
  mfa_softmax<<<NN / 256, 256, 0, stream>>>(out);
}

// Round 8
// 74.100 us; speedup vs baseline: 1.1297x; 1.1297x over previous
//
#include <hip/hip_runtime.h>
#include <math.h>

#define MM 32
#define NN 8192
#define DD 64
#define KK 16

typedef float f32x4 __attribute__((ext_vector_type(4)));

// ---------------------------------------------------------------------------
// Kernel 1: lite per-component precompute via Woodbury. 32 blocks x 64 thr.
//   Mk = I + Lambda^T P^{-1} Lambda (16x16); Minv[m] = Mk^{-1};
//   cconst[m] = log(pi+1e-10) - 0.5*(D log2pi + logdetP + logdetM)
// Thread t owns column j = t&15 (k-chunks t>>4 + 4r), logs parallelized.
// ---------------------------------------------------------------------------
__global__ __launch_bounds__(64) void mfa_pre(
    const float* __restrict__ pi, const float* __restrict__ Lambda,
    const float* __restrict__ Psi, float* __restrict__ Minv_out,
    float* __restrict__ const_out) {
  const int m = blockIdx.x;
  const int t = threadIdx.x;
  __shared__ float lam[DD * KK];   // 4KB
  __shared__ float pinv[DD];
  __shared__ float Mmat[KK * KK];
  __shared__ float Lmat[KK * KK];
  __shared__ float vbuf[KK];
  __shared__ float red[DD];

  const float4* Lg = reinterpret_cast<const float4*>(Lambda + (size_t)m * DD * KK);
  float4* lam4 = reinterpret_cast<float4*>(lam);
  for (int i = t; i < DD * KK / 4; i += 64) lam4[i] = Lg[i];
  if (t < DD) pinv[t] = 1.0f / (Psi[t] + 1e-6f);
  __syncthreads();

  // Mk: thread t -> column j = t&15, rows k = (t>>4) + 4r (4 entries).
  {
    const int j = t & 15;
    const int k0 = t >> 4;
    float acc[4] = {0.f, 0.f, 0.f, 0.f};
    for (int d = 0; d < DD; ++d) {
      const float cj = lam[d * KK + j] * pinv[d];
#pragma unroll
      for (int r = 0; r < 4; ++r) acc[r] += lam[d * KK + (k0 + 4 * r)] * cj;
    }
#pragma unroll
    for (int r = 0; r < 4; ++r) {
      const int k = k0 + 4 * r;
      Mmat[k * KK + j] = acc[r] + (k == j ? 1.0f : 0.0f);
    }
  }
  __syncthreads();

  // Cooperative right-looking Cholesky: thread r owns row r in registers.
  float lr[KK];
  if (t < KK) {
#pragma unroll
    for (int j = 0; j < KK; ++j) lr[j] = Mmat[t * KK + j];
  }
#pragma unroll
  for (int c = 0; c < KK; ++c) {
    if (t < KK) vbuf[t] = lr[c];
    __syncthreads();
    if (t < KK) {
      const float vc = vbuf[c];
      const float dc = sqrtf(vc);
      if (t >= c) Lmat[t * KK + c] = lr[c] / dc;
      const float s = lr[c] / vc;
#pragma unroll
      for (int j = 0; j < KK; ++j)
        if (j > c) lr[j] -= s * vbuf[j];
    }
    __syncthreads();
  }

  // parallel logs (vbuf free after loop; red fresh)
  if (t < DD) red[t] = logf(pinv[t]);
  if (t < KK) vbuf[t] = logf(Lmat[t * KK + t]);

  // Minv via two triangular solves per unit column (thread = column).
  if (t < KK) {
    const int col = t;
    float y[KK], z[KK];
#pragma unroll
    for (int i = 0; i < KK; ++i) {
      float s = (i == col) ? 1.0f : 0.0f;
#pragma unroll
      for (int p = 0; p < KK; ++p)
        if (p < i) s -= Lmat[i * KK + p] * y[p];
      y[i] = s / Lmat[i * KK + i];
    }
#pragma unroll
    for (int i = KK - 1; i >= 0; --i) {
      float s = y[i];
#pragma unroll
      for (int p = 0; p < KK; ++p)
        if (p > i) s -= Lmat[p * KK + i] * z[p];
      z[i] = s / Lmat[i * KK + i];
    }
#pragma unroll
    for (int i = 0; i < KK; ++i)
      Minv_out[(size_t)m * KK * KK + i * KK + col] = z[i];
  }
  __syncthreads();

  if (t == 0) {
    float sl = 0.0f;  // sum log pinv  (logdetP = -sl)
    for (int d = 0; d < DD; ++d) sl += red[d];
    float lM = 0.0f;
#pragma unroll
    for (int c = 0; c < KK; ++c) lM += vbuf[c];
    const float LOG2PI = 1.8378770664093453f;
    const_out[m] =
        logf(pi[m] + 1e-10f) - 0.5f * (DD * LOG2PI - sl + 2.0f * lM);
  }
}

// ---------------------------------------------------------------------------
// Kernel 2: fused main pass (R6 structure, cached stores). Params read as
// uniform global loads (Lambda direct + dfp trick — no Wl precompute;
// pinv via rcpf of uniform Psi). Logits go to contiguous scratch [M,N]
// (1KB full-line writes per block — no cross-XCD partial-line ping-pong).
// ez staged via ds_write_b128. Store phase: wave-local, coalesced 1KB tiles.
// ---------------------------------------------------------------------------
__global__ __launch_bounds__(256) void mfa_main(
    const float* __restrict__ X, const float* __restrict__ mu,
    const float* __restrict__ Lambda, const float* __restrict__ Psi,
    const float* __restrict__ Minv, const float* __restrict__ cconst,
    float* __restrict__ scr, float* __restrict__ out) {
  const int m = blockIdx.y;
  const int n0 = blockIdx.x * 256;
  const int tid = threadIdx.x;
  const int w = tid >> 6, l = tid & 63;

  __shared__ float ez_l[256 * KK];  // 16KB, wave w owns [w*64*KK, +4KB)

  const float* lamG = Lambda + (size_t)m * DD * KK;  // uniform rows
  const float* mum = mu + m * DD;
  const float* Mi = Minv + (size_t)m * KK * KK;
  const float cst = cconst[m];

  const int n = n0 + tid;

  float u[KK];
#pragma unroll
  for (int k = 0; k < KK; ++k) u[k] = 0.0f;
  float q = 0.0f;
  const float4* X4 = reinterpret_cast<const float4*>(X + (size_t)n * DD);
#pragma unroll
  for (int d4 = 0; d4 < DD / 4; ++d4) {
    const float4 xv = X4[d4];                                           // lane
    const float4 muv = *reinterpret_cast<const float4*>(mum + d4 * 4);  // unif
    const float4 psv = *reinterpret_cast<const float4*>(Psi + d4 * 4);  // unif
    const float xs[4] = {xv.x, xv.y, xv.z, xv.w};
    const float ms[4] = {muv.x, muv.y, muv.z, muv.w};
    const float ps[4] = {psv.x, psv.y, psv.z, psv.w};
#pragma unroll
    for (int s = 0; s < 4; ++s) {
      const int d = d4 * 4 + s;
      const float df = xs[s] - ms[s];
      const float dfp = df * __builtin_amdgcn_rcpf(ps[s] + 1e-6f);
      q += df * dfp;
      const float4* wr = reinterpret_cast<const float4*>(lamG + d * KK);
#pragma unroll
      for (int k4 = 0; k4 < 4; ++k4) {
        const float4 wv = wr[k4];  // uniform
        u[k4 * 4 + 0] += wv.x * dfp;
        u[k4 * 4 + 1] += wv.y * dfp;
        u[k4 * 4 + 2] += wv.z * dfp;
        u[k4 * 4 + 3] += wv.w * dfp;
      }
    }
  }

  // e_z = Minv u (computed as f32x4 quads -> ds_write_b128), udot alongside
  float udot = 0.0f;
  float* ezrow = ez_l + (size_t)tid * KK;
#pragma unroll
  for (int i4 = 0; i4 < 4; ++i4) {
    f32x4 ezv;
#pragma unroll
    for (int ii = 0; ii < 4; ++ii) {
      const int i = i4 * 4 + ii;
      const float4* mr = reinterpret_cast<const float4*>(Mi + i * KK);
      float s = 0.0f;
#pragma unroll
      for (int j4 = 0; j4 < 4; ++j4) {
        const float4 mv = mr[j4];  // uniform
        s += mv.x * u[j4 * 4 + 0] + mv.y * u[j4 * 4 + 1] +
             mv.z * u[j4 * 4 + 2] + mv.w * u[j4 * 4 + 3];
      }
      ezv[ii] = s;
      udot += u[i] * s;
    }
    *reinterpret_cast<f32x4*>(ezrow + i4 * 4) = ezv;
  }
  scr[(size_t)m * NN + n] = cst - 0.5f * (q - udot);  // contiguous logit

  // ---- wave-local phase switch (no __syncthreads) ----
  __builtin_amdgcn_wave_barrier();
  asm volatile("s_waitcnt lgkmcnt(0)" ::: "memory");

  const int sbase = n0 + w * 64;  // first sample owned by this wave
  const f32x4* ezl4 =
      reinterpret_cast<const f32x4*>(ez_l + (size_t)w * 64 * KK);

  // e_z out: wave's 64 samples * 16 floats = 256 float4, coalesced
  f32x4* ezo = reinterpret_cast<f32x4*>(
      out + (size_t)NN * MM + ((size_t)m * NN + sbase) * KK);
#pragma unroll
  for (int it = 0; it < 4; ++it) ezo[it * 64 + l] = ezl4[it * 64 + l];

  // e_zz out: per iteration the wave writes one sample's full 16x16 tile
  // (64 lanes x float4 = 1KB, coalesced). lane l: row l>>2, col-quad l&3.
  const int i_ = l >> 2, jq = l & 3;
  const f32x4 mreg = reinterpret_cast<const f32x4*>(Mi)[l];  // per-lane
  f32x4* zzo = reinterpret_cast<f32x4*>(out + (size_t)NN * MM +
                                        (size_t)MM * NN * KK) +
               ((size_t)m * NN + sbase) * 64;
#pragma unroll 4
  for (int nl = 0; nl < 64; ++nl) {
    const float ezi = ez_l[((size_t)w * 64 + nl) * KK + i_];
    const f32x4 ezj = ezl4[nl * 4 + jq];
    zzo[nl * 64 + l] = mreg + ezi * ezj;
  }
}

// ---------------------------------------------------------------------------
// Kernel 3: softmax. 128 blocks x 64 threads. Reads scratch [M,N]
// (coalesced 256B per m across the wave), writes resp [N,M] coalesced.
// ---------------------------------------------------------------------------
__global__ __launch_bounds__(64) void mfa_softmax(
    const float* __restrict__ scr, float* __restrict__ out) {
  const int n = blockIdx.x * 64 + threadIdx.x;
  float v[MM];
#pragma unroll
  for (int m = 0; m < MM; ++m) v[m] = scr[(size_t)m * NN + n];
  float mx = -3.4e38f;
#pragma unroll
  for (int i = 0; i < MM; ++i) mx = fmaxf(mx, v[i]);
  float s = 0.0f;
#pragma unroll
  for (int i = 0; i < MM; ++i) { v[i] = expf(v[i] - mx); s += v[i]; }
  const float inv = 1.0f / s;
  float4* p = reinterpret_cast<float4*>(out) + (size_t)n * (MM / 4);
#pragma unroll
  for (int i = 0; i < MM / 4; ++i) {
    float4 t;
    t.x = v[4 * i] * inv; t.y = v[4 * i + 1] * inv;
    t.z = v[4 * i + 2] * inv; t.w = v[4 * i + 3] * inv;
    p[i] = t;
  }
}

extern "C" void kernel_launch(void* const* d_in, const int* in_sizes, int n_in,
                              void* d_out, int out_size, void* d_ws,
                              size_t ws_size, hipStream_t stream) {
  const float* X = (const float*)d_in[0];
  const float* pi = (const float*)d_in[1];
  const float* mu = (const float*)d_in[2];
  const float* Lambda = (const float*)d_in[3];
  const float* Psi = (const float*)d_in[4];
  float* out = (float*)d_out;

  float* Minv = (float*)d_ws;            // 32*256 floats
  float* cconst = Minv + MM * KK * KK;   // 32
  float* scr = cconst + MM;              // 32*8192 floats = 1MB

  mfa_pre<<<MM, 64, 0, stream>>>(pi, Lambda, Psi, Minv, cconst);
  mfa_main<<<dim3(NN / 256, MM), 256, 0, stream>>>(X, mu, Lambda, Psi, Minv,
                                                   cconst, scr, out);
  mfa_softmax<<<NN / 64, 64, 0, stream>>>(scr, out);
}